// Round 1
// baseline (75.336 us; speedup 1.0000x reference)
//
#include <hip/hip_runtime.h>

// FeatureLayer: out[row] = concat( sum_k W_item[item_hist[row,k]],        (64)
//                                  mean_k W_cate[cate_hist[row,k]],       (64)
//                                  concat_k W_ctx[ctx_ids[row,k]],        (640)
//                                  price[row],                            (1)
//                                  dense_vec[row] )                       (128)
// padding_idx = 0: index 0 contributes zeros. Mean divides by L=50 incl. padding.

#define LH 50      // item/cate history length
#define LC 20      // ctx length
#define DI 64      // item emb dim
#define DC 64      // cate emb dim
#define DX 32      // ctx emb dim
#define DDENSE 128
#define OUT_D 897  // 64 + 64 + 640 + 1 + 128

__global__ __launch_bounds__(256) void featlayer_kernel(
    const int* __restrict__ item_hist,
    const int* __restrict__ cate_hist,
    const int* __restrict__ ctx_ids,
    const float* __restrict__ price,
    const float* __restrict__ dense_vec,
    const float* __restrict__ W_item,
    const float* __restrict__ W_cate,
    const float* __restrict__ W_ctx,
    float* __restrict__ out,
    int B)
{
    const int wave = threadIdx.x >> 6;
    const int lane = threadIdx.x & 63;
    const int row  = blockIdx.x * 4 + wave;
    if (row >= B) return;

    const int sub = lane >> 4;   // 0..3 : which index within a group of 4
    const int l16 = lane & 15;   // 0..15: which float4 of the 64-wide emb row

    float* __restrict__ orow = out + (size_t)row * OUT_D;

    // ---------------- item: sum merger ----------------
    {
        const int* __restrict__ ih = item_hist + row * LH;
        float ax = 0.f, ay = 0.f, az = 0.f, aw = 0.f;
        for (int k = sub; k < LH; k += 4) {
            const int idx = ih[k];
            const float4 v = *reinterpret_cast<const float4*>(
                W_item + ((size_t)idx * DI + l16 * 4));
            const float s = (idx != 0) ? 1.0f : 0.0f;  // padding_idx
            ax += v.x * s; ay += v.y * s; az += v.z * s; aw += v.w * s;
        }
        // combine 4 sub-group partials (lanes l, l+16, l+32, l+48)
        ax += __shfl_xor(ax, 16, 64); ay += __shfl_xor(ay, 16, 64);
        az += __shfl_xor(az, 16, 64); aw += __shfl_xor(aw, 16, 64);
        ax += __shfl_xor(ax, 32, 64); ay += __shfl_xor(ay, 32, 64);
        az += __shfl_xor(az, 32, 64); aw += __shfl_xor(aw, 32, 64);
        if (sub == 0) {
            float* o = orow + l16 * 4;
            o[0] = ax; o[1] = ay; o[2] = az; o[3] = aw;
        }
    }

    // ---------------- cate: mean merger ----------------
    {
        const int* __restrict__ ch = cate_hist + row * LH;
        float ax = 0.f, ay = 0.f, az = 0.f, aw = 0.f;
        for (int k = sub; k < LH; k += 4) {
            const int idx = ch[k];
            const float4 v = *reinterpret_cast<const float4*>(
                W_cate + ((size_t)idx * DC + l16 * 4));
            const float s = (idx != 0) ? 1.0f : 0.0f;
            ax += v.x * s; ay += v.y * s; az += v.z * s; aw += v.w * s;
        }
        ax += __shfl_xor(ax, 16, 64); ay += __shfl_xor(ay, 16, 64);
        az += __shfl_xor(az, 16, 64); aw += __shfl_xor(aw, 16, 64);
        ax += __shfl_xor(ax, 32, 64); ay += __shfl_xor(ay, 32, 64);
        az += __shfl_xor(az, 32, 64); aw += __shfl_xor(aw, 32, 64);
        if (sub == 0) {
            const float inv = 1.0f / (float)LH;  // mean divides by L incl. padding
            float* o = orow + DI + l16 * 4;
            o[0] = ax * inv; o[1] = ay * inv; o[2] = az * inv; o[3] = aw * inv;
        }
    }

    // ---------------- ctx: concat merger (640 floats) ----------------
    {
        const int* __restrict__ cx = ctx_ids + row * LC;
        #pragma unroll
        for (int j = lane; j < LC * DX; j += 64) {
            const int idx = cx[j >> 5];             // which of the 20 ids
            const int d   = j & 31;                 // dim within 32
            orow[DI + DC + j] = (idx != 0) ? W_ctx[idx * DX + d] : 0.0f;
        }
    }

    // ---------------- price (1) + dense (128) ----------------
    if (lane == 0) orow[DI + DC + LC * DX] = price[row];
    {
        const float* __restrict__ dv = dense_vec + (size_t)row * DDENSE;
        orow[DI + DC + LC * DX + 1 + lane]      = dv[lane];
        orow[DI + DC + LC * DX + 1 + 64 + lane] = dv[64 + lane];
    }
}

extern "C" void kernel_launch(void* const* d_in, const int* in_sizes, int n_in,
                              void* d_out, int out_size, void* d_ws, size_t ws_size,
                              hipStream_t stream) {
    const int*   item_hist = (const int*)  d_in[0];
    const int*   cate_hist = (const int*)  d_in[1];
    const int*   ctx_ids   = (const int*)  d_in[2];
    const float* price     = (const float*)d_in[3];
    const float* dense_vec = (const float*)d_in[4];
    const float* W_item    = (const float*)d_in[5];
    const float* W_cate    = (const float*)d_in[6];
    const float* W_ctx     = (const float*)d_in[7];
    float* out = (float*)d_out;

    const int B = in_sizes[0] / LH;         // 16384
    const int grid = (B + 3) / 4;           // 4 rows per 256-thread block
    featlayer_kernel<<<grid, 256, 0, stream>>>(
        item_hist, cate_hist, ctx_ids, price, dense_vec,
        W_item, W_cate, W_ctx, out, B);
}